// Round 12
// baseline (294.559 us; speedup 1.0000x reference)
//
#include <hip/hip_runtime.h>
#include <hip/hip_bf16.h>

// B=16, S=512, D=64, V=32000.
// Pipeline (refactored by associativity):
//   emb, n2        (K1a)     W' = out_w @ w2 -> bf16   (K1b, same launch)
//   attn_u, invs   (K2)
//   h1 = invs*(attn_u@emb)@w1^T          (K3: prop+proj fused via LDS epilogue)
//   hb = bf16(invs*(attn_u@h1))          (K4: pure prop)
//   logits = hb @ W'^T                   (K5: r11's proven logits kernel)
// 5 launches. Error structure identical to r11 (single bf16 cast pair at K5).

#define S_ 512
#define D_ 64
#define V_ 32000

typedef __attribute__((ext_vector_type(8))) __bf16 bf16x8;
typedef __attribute__((ext_vector_type(4))) float f32x4;

__device__ inline unsigned short f2bf(float x) {
    __hip_bfloat16 h = __float2bfloat16(x);
    return __builtin_bit_cast(unsigned short, h);
}

// ---- K1 (fat): blocks [0,2048): embed rows; blocks [2048,4048): W' = outw@w2 ----
__global__ __launch_bounds__(256) void embed_wprime_kernel(const int* __restrict__ tokens,
                                                           const float* __restrict__ temb,
                                                           float* __restrict__ emb,
                                                           float* __restrict__ n2,
                                                           const float* __restrict__ outw,
                                                           const float* __restrict__ w2,
                                                           unsigned short* __restrict__ wb) {
    __shared__ float os[16][68];
    __shared__ float w2t[64][68];
    int bid = blockIdx.x;
    if (bid < 2048) {
        // ---------- embed ----------
        int row  = bid * 4 + (threadIdx.x >> 6);
        int lane = threadIdx.x & 63;
        int s    = row & (S_ - 1);
        int tok  = tokens[row];
        float val;
        if (lane < 2) {
            float fs    = (float)s;
            float theta = 6.283185307179586f * (fs * (1.0f / 512.0f));
            float r     = 0.3f + 0.6f * (fs * (1.0f / 511.0f));
            val = (lane == 0) ? r * cosf(theta) : r * sinf(theta);
        } else {
            val = temb[tok * D_ + lane - 2];
        }
        float ss = val * val;
#pragma unroll
        for (int off = 32; off; off >>= 1) ss += __shfl_xor(ss, off, 64);
        float nrm = sqrtf(fmaxf(ss, 1e-12f));
        float e   = val / nrm;
        emb[row * D_ + lane] = e;
        float nn = e * e;
#pragma unroll
        for (int off = 32; off; off >>= 1) nn += __shfl_xor(nn, off, 64);
        if (lane == 0) n2[row] = nn;
    } else {
        // ---------- W'[v][e] = sum_d outw[v][d] * w2[d][e], bf16 out ----------
        int r0 = (bid - 2048) * 16;
        int t  = threadIdx.x;
        {   // outw rows 16x64
            int r = t >> 4, c4 = (t & 15) * 4;
            *reinterpret_cast<float4*>(&os[r][c4]) =
                *reinterpret_cast<const float4*>(&outw[(size_t)(r0 + r) * D_ + c4]);
        }
#pragma unroll
        for (int j = 0; j < 4; ++j) {   // w2 transposed into w2t[e][d]
            int f4 = t + j * 256;
            int d = f4 >> 4, c4 = (f4 & 15) * 4;
            float4 v = *reinterpret_cast<const float4*>(&w2[d * D_ + c4]);
            w2t[c4 + 0][d] = v.x; w2t[c4 + 1][d] = v.y;
            w2t[c4 + 2][d] = v.z; w2t[c4 + 3][d] = v.w;
        }
        __syncthreads();
        int q = t >> 4, eh = t & 15;
        f32x4 acc[4];
#pragma unroll
        for (int ej = 0; ej < 4; ++ej) acc[ej] = (f32x4){0.f, 0.f, 0.f, 0.f};
#pragma unroll
        for (int dc = 0; dc < 16; ++dc) {
            f32x4 ov = *reinterpret_cast<f32x4*>(&os[q][dc * 4]);
#pragma unroll
            for (int ej = 0; ej < 4; ++ej) {
                f32x4 wv = *reinterpret_cast<f32x4*>(&w2t[eh * 4 + ej][dc * 4]);
                acc[ej] += ov * wv;
            }
        }
        ushort4 r;
        r.x = f2bf((acc[0][0] + acc[0][1]) + (acc[0][2] + acc[0][3]));
        r.y = f2bf((acc[1][0] + acc[1][1]) + (acc[1][2] + acc[1][3]));
        r.z = f2bf((acc[2][0] + acc[2][1]) + (acc[2][2] + acc[2][3]));
        r.w = f2bf((acc[3][0] + acc[3][1]) + (acc[3][2] + acc[3][3]));
        *reinterpret_cast<ushort4*>(&wb[(size_t)(r0 + q) * D_ + eh * 4]) = r;
    }
}

// ------- K2 attention: attn_u[b][q][k] = exp(-dist) (unnorm), invs = scale/rowsum ----
__global__ __launch_bounds__(128) void attn_kernel(const float* __restrict__ emb,
                                                   const float* __restrict__ n2,
                                                   const float* __restrict__ edge_scale,
                                                   float* __restrict__ attn_u,
                                                   float* __restrict__ invs) {
    __shared__ float qs[16][68];
    __shared__ float ks[64][68];
    __shared__ float n2qs[16];
    __shared__ float n2ks[64];
    int b  = blockIdx.x >> 5;
    int q0 = (blockIdx.x & 31) * 16;
    int t  = threadIdx.x;           // 0..127
    const float* ebase = emb + (size_t)b * S_ * D_;
#pragma unroll
    for (int j = 0; j < 2; ++j) {
        int f4 = t + j * 128;
        int r = f4 >> 4, c4 = (f4 & 15) * 4;
        *reinterpret_cast<float4*>(&qs[r][c4]) =
            *reinterpret_cast<const float4*>(&ebase[(q0 + r) * D_ + c4]);
    }
    if (t < 16) n2qs[t] = n2[b * S_ + q0 + t];

    int qg = t >> 4;   // q rows qg*2+i
    int kg = t & 15;   // k cols kg*4+j
    float rs[2] = {0.f, 0.f};

    for (int kt = 0; kt < 8; ++kt) {
        int k0 = kt * 64;
        __syncthreads();
#pragma unroll
        for (int j = 0; j < 8; ++j) {
            int f4 = t + j * 128;
            int r = f4 >> 4, c4 = (f4 & 15) * 4;
            *reinterpret_cast<float4*>(&ks[r][c4]) =
                *reinterpret_cast<const float4*>(&ebase[(k0 + r) * D_ + c4]);
        }
        if (t < 64) n2ks[t] = n2[b * S_ + k0 + t];
        __syncthreads();

        f32x4 acc[2][4];
#pragma unroll
        for (int i = 0; i < 2; ++i)
#pragma unroll
            for (int j = 0; j < 4; ++j) acc[i][j] = (f32x4){0.f, 0.f, 0.f, 0.f};
#pragma unroll
        for (int dc = 0; dc < 16; ++dc) {
            f32x4 qv[2], kv[4];
#pragma unroll
            for (int i = 0; i < 2; ++i) qv[i] = *reinterpret_cast<f32x4*>(&qs[qg * 2 + i][dc * 4]);
#pragma unroll
            for (int j = 0; j < 4; ++j) kv[j] = *reinterpret_cast<f32x4*>(&ks[kg * 4 + j][dc * 4]);
#pragma unroll
            for (int i = 0; i < 2; ++i)
#pragma unroll
                for (int j = 0; j < 4; ++j) acc[i][j] += qv[i] * kv[j];
        }
#pragma unroll
        for (int i = 0; i < 2; ++i) {
            int q = qg * 2 + i;
            float4 ev;
            float* evp = &ev.x;
#pragma unroll
            for (int j = 0; j < 4; ++j) {
                int k = kg * 4 + j;
                f32x4 a = acc[i][j];
                float dot = (a[0] + a[1]) + (a[2] + a[3]);
                float sq  = n2qs[q] + n2ks[k] - 2.0f * dot;
                evp[j] = (q0 + q == k0 + k) ? 1.0f : __expf(-sqrtf(fmaxf(sq, 1e-12f)));
            }
            rs[i] += (ev.x + ev.y) + (ev.z + ev.w);
            *reinterpret_cast<float4*>(
                &attn_u[((size_t)(b * S_ + q0 + q)) * S_ + k0 + kg * 4]) = ev;
        }
    }
    float scale = edge_scale[0];
#pragma unroll
    for (int i = 0; i < 2; ++i) {
#pragma unroll
        for (int off = 1; off < 16; off <<= 1) rs[i] += __shfl_xor(rs[i], off, 64);
        if (kg == 0) invs[b * S_ + q0 + qg * 2 + i] = scale / rs[i];
    }
}

// ------- K3: h1 = invs * (attn_u @ emb) @ w1^T  (prop + proj fused) --------
__global__ __launch_bounds__(128) void prop_proj_kernel(const float* __restrict__ attn_u,
                                                        const float* __restrict__ hsrc,
                                                        const float* __restrict__ w1,
                                                        const float* __restrict__ invs,
                                                        float* __restrict__ outf) {
    __shared__ float As[16][68];
    __shared__ float Ts[64][68];
    __shared__ float ws1[64][68];
    __shared__ float gs[16][68];
    int b  = blockIdx.x >> 5;
    int q0 = (blockIdx.x & 31) * 16;
    int t  = threadIdx.x;           // 0..127
    int qg = t >> 4, dh = t & 15;
#pragma unroll
    for (int j = 0; j < 8; ++j) {   // stage w1 rows (w1^T access = row-major rows)
        int f4 = t + j * 128;
        int r = f4 >> 4, c4 = (f4 & 15) * 4;
        *reinterpret_cast<float4*>(&ws1[r][c4]) =
            *reinterpret_cast<const float4*>(&w1[r * D_ + c4]);
    }
    f32x4 acc[2];
#pragma unroll
    for (int i = 0; i < 2; ++i) acc[i] = (f32x4){0.f, 0.f, 0.f, 0.f};
    const float* abase = attn_u + ((size_t)b * S_ + q0) * S_;
    const float* tbase = hsrc + (size_t)b * S_ * D_;
    for (int kt = 0; kt < 8; ++kt) {
        int k0 = kt * 64;
        __syncthreads();
#pragma unroll
        for (int j = 0; j < 2; ++j) {
            int f4 = t + j * 128;
            int r = f4 >> 4, c4 = (f4 & 15) * 4;
            *reinterpret_cast<float4*>(&As[r][c4]) =
                *reinterpret_cast<const float4*>(&abase[(size_t)r * S_ + k0 + c4]);
        }
#pragma unroll
        for (int j = 0; j < 8; ++j) {
            int f4 = t + j * 128;
            int r = f4 >> 4, c4 = (f4 & 15) * 4;
            *reinterpret_cast<float4*>(&Ts[r][c4]) =
                *reinterpret_cast<const float4*>(&tbase[(k0 + r) * D_ + c4]);
        }
        __syncthreads();
#pragma unroll
        for (int kc = 0; kc < 16; ++kc) {
            f32x4 tv[4];
#pragma unroll
            for (int ks = 0; ks < 4; ++ks)
                tv[ks] = *reinterpret_cast<f32x4*>(&Ts[kc * 4 + ks][dh * 4]);
#pragma unroll
            for (int i = 0; i < 2; ++i) {
                f32x4 av = *reinterpret_cast<f32x4*>(&As[qg * 2 + i][kc * 4]);
#pragma unroll
                for (int ks = 0; ks < 4; ++ks) acc[i] += av[ks] * tv[ks];
            }
        }
    }
    // stage g = attn_u @ hsrc, then epilogue: h1 = invs * g @ w1^T
#pragma unroll
    for (int i = 0; i < 2; ++i) {
        f32x4 v = acc[i];
        *reinterpret_cast<float4*>(&gs[qg * 2 + i][dh * 4]) =
            make_float4(v[0], v[1], v[2], v[3]);
    }
    __syncthreads();
    f32x4 acc2[2][4];
#pragma unroll
    for (int i = 0; i < 2; ++i)
#pragma unroll
        for (int dj = 0; dj < 4; ++dj) acc2[i][dj] = (f32x4){0.f, 0.f, 0.f, 0.f};
#pragma unroll
    for (int dc = 0; dc < 16; ++dc) {
        f32x4 wv[4];
#pragma unroll
        for (int dj = 0; dj < 4; ++dj)
            wv[dj] = *reinterpret_cast<f32x4*>(&ws1[dh * 4 + dj][dc * 4]);
#pragma unroll
        for (int i = 0; i < 2; ++i) {
            f32x4 gv = *reinterpret_cast<f32x4*>(&gs[qg * 2 + i][dc * 4]);
#pragma unroll
            for (int dj = 0; dj < 4; ++dj) acc2[i][dj] += gv * wv[dj];
        }
    }
#pragma unroll
    for (int i = 0; i < 2; ++i) {
        int row = b * S_ + q0 + qg * 2 + i;
        float inv = invs[row];
        float4 r;
        r.x = inv * ((acc2[i][0][0] + acc2[i][0][1]) + (acc2[i][0][2] + acc2[i][0][3]));
        r.y = inv * ((acc2[i][1][0] + acc2[i][1][1]) + (acc2[i][1][2] + acc2[i][1][3]));
        r.z = inv * ((acc2[i][2][0] + acc2[i][2][1]) + (acc2[i][2][2] + acc2[i][2][3]));
        r.w = inv * ((acc2[i][3][0] + acc2[i][3][1]) + (acc2[i][3][2] + acc2[i][3][3]));
        *reinterpret_cast<float4*>(&outf[(size_t)row * D_ + dh * 4]) = r;
    }
}

// ------- K4: hb = bf16(invs * (attn_u @ h1))  (pure prop, bf16 out) --------
__global__ __launch_bounds__(128) void prop_kernel(const float* __restrict__ attn_u,
                                                   const float* __restrict__ tmat,
                                                   const float* __restrict__ invs,
                                                   unsigned short* __restrict__ outb) {
    __shared__ float As[16][68];
    __shared__ float Ts[64][68];
    int b  = blockIdx.x >> 5;
    int q0 = (blockIdx.x & 31) * 16;
    int t  = threadIdx.x;           // 0..127
    int qg = t >> 4, dh = t & 15;
    f32x4 acc[2];
#pragma unroll
    for (int i = 0; i < 2; ++i) acc[i] = (f32x4){0.f, 0.f, 0.f, 0.f};
    const float* abase = attn_u + ((size_t)b * S_ + q0) * S_;
    const float* tbase = tmat + (size_t)b * S_ * D_;
    for (int kt = 0; kt < 8; ++kt) {
        int k0 = kt * 64;
        __syncthreads();
#pragma unroll
        for (int j = 0; j < 2; ++j) {
            int f4 = t + j * 128;
            int r = f4 >> 4, c4 = (f4 & 15) * 4;
            *reinterpret_cast<float4*>(&As[r][c4]) =
                *reinterpret_cast<const float4*>(&abase[(size_t)r * S_ + k0 + c4]);
        }
#pragma unroll
        for (int j = 0; j < 8; ++j) {
            int f4 = t + j * 128;
            int r = f4 >> 4, c4 = (f4 & 15) * 4;
            *reinterpret_cast<float4*>(&Ts[r][c4]) =
                *reinterpret_cast<const float4*>(&tbase[(k0 + r) * D_ + c4]);
        }
        __syncthreads();
#pragma unroll
        for (int kc = 0; kc < 16; ++kc) {
            f32x4 tv[4];
#pragma unroll
            for (int ks = 0; ks < 4; ++ks)
                tv[ks] = *reinterpret_cast<f32x4*>(&Ts[kc * 4 + ks][dh * 4]);
#pragma unroll
            for (int i = 0; i < 2; ++i) {
                f32x4 av = *reinterpret_cast<f32x4*>(&As[qg * 2 + i][kc * 4]);
#pragma unroll
                for (int ks = 0; ks < 4; ++ks) acc[i] += av[ks] * tv[ks];
            }
        }
    }
#pragma unroll
    for (int i = 0; i < 2; ++i) {
        int row = b * S_ + q0 + qg * 2 + i;
        float inv = invs[row];
        ushort4 r;
        r.x = f2bf(inv * acc[i][0]); r.y = f2bf(inv * acc[i][1]);
        r.z = f2bf(inv * acc[i][2]); r.w = f2bf(inv * acc[i][3]);
        *reinterpret_cast<ushort4*>(&outb[(size_t)row * D_ + dh * 4]) = r;
    }
}

// ---------------- K5 logits: out[8192,32000] = hb @ W'^T  (bf16 MFMA) ----------------
// r11's kernel: 128x256 tile, streaming per-16-rows, dbuf LDS stage,
// 1 row x 1024B contiguous per store instr, single barrier per iter.
__global__ __launch_bounds__(256) void logits_kernel(const unsigned short* __restrict__ hb,
                                                     const unsigned short* __restrict__ wb,
                                                     float* __restrict__ out) {
    __shared__ float Ct[2][16][260];
    int bid = blockIdx.x;
    int nt = bid % 125, mt = bid / 125;
    int n0 = nt * 256, m0 = mt * 128;
    int wave = threadIdx.x >> 6, lane = threadIdx.x & 63;
    int lr = lane & 15, lh = lane >> 4;

    bf16x8 a[2][2][2];
#pragma unroll
    for (int c = 0; c < 2; ++c)
#pragma unroll
        for (int ns = 0; ns < 2; ++ns)
#pragma unroll
            for (int kh = 0; kh < 2; ++kh)
                a[c][ns][kh] = *reinterpret_cast<const bf16x8*>(
                    wb + (size_t)(n0 + wave * 64 + c * 32 + ns * 16 + lr) * D_ + kh * 32 + lh * 8);

    for (int ms = 0; ms < 8; ++ms) {
        const unsigned short* hrow = hb + (size_t)(m0 + ms * 16 + lr) * D_ + lh * 8;
        bf16x8 b0 = *reinterpret_cast<const bf16x8*>(hrow);
        bf16x8 b1 = *reinterpret_cast<const bf16x8*>(hrow + 32);
        f32x4 acc[2][2];
#pragma unroll
        for (int c = 0; c < 2; ++c)
#pragma unroll
            for (int ns = 0; ns < 2; ++ns) {
                acc[c][ns] = (f32x4){0.f, 0.f, 0.f, 0.f};
                acc[c][ns] = __builtin_amdgcn_mfma_f32_16x16x32_bf16(a[c][ns][0], b0, acc[c][ns], 0, 0, 0);
                acc[c][ns] = __builtin_amdgcn_mfma_f32_16x16x32_bf16(a[c][ns][1], b1, acc[c][ns], 0, 0, 0);
            }

        float* Lw = &Ct[ms & 1][lr][wave * 64];
#pragma unroll
        for (int c = 0; c < 2; ++c)
#pragma unroll
            for (int ns = 0; ns < 2; ++ns) {
                f32x4 v = acc[c][ns];
                *reinterpret_cast<float4*>(Lw + c * 32 + ns * 16 + lh * 4) =
                    make_float4(v[0], v[1], v[2], v[3]);
            }
        __syncthreads();

#pragma unroll
        for (int j = 0; j < 4; ++j) {
            int row = wave * 4 + j;
            const float* Lr = &Ct[ms & 1][row][lane * 4];
            float4 v = *reinterpret_cast<const float4*>(Lr);
            *reinterpret_cast<float4*>(out + (size_t)(m0 + ms * 16 + row) * V_ + n0 + lane * 4) = v;
        }
        // no trailing barrier (dbuf spans the WAR hazard across two barriers)
    }
}

extern "C" void kernel_launch(void* const* d_in, const int* in_sizes, int n_in,
                              void* d_out, int out_size, void* d_ws, size_t ws_size,
                              hipStream_t stream) {
    const int*   tokens = (const int*)d_in[0];
    const float* temb   = (const float*)d_in[1];
    const float* w1     = (const float*)d_in[2];
    const float* w2     = (const float*)d_in[3];
    const float* escale = (const float*)d_in[4];
    const float* outw   = (const float*)d_in[5];
    float*       out    = (float*)d_out;

    // Large scratch in tail of d_out (1,048,576,000 B); consumed before logits.
    char* tail = (char*)d_out + 1048576000ull - 23068672ull;
    float* attn = (float*)(tail);                   // 16 MB (unnormalized exp)
    float* emb  = (float*)(tail + 16777216);        // 2 MB
    float* h1   = (float*)(tail + 18874368);        // 2 MB

    // Small scratch in d_ws (~5.25 MB).
    char* ws = (char*)d_ws;
    unsigned short* hb   = (unsigned short*)(ws);             // 1 MB
    unsigned short* wb   = (unsigned short*)(ws + 1048576);   // 4 MB (= W')
    float*          n2   = (float*)(ws + 5144576);            // 32 KB
    float*          invs = (float*)(ws + 5177344);            // 32 KB

    embed_wprime_kernel<<<4048, 256, 0, stream>>>(tokens, temb, emb, n2, outw, w2, wb);
    attn_kernel<<<512, 128, 0, stream>>>(emb, n2, escale, attn, invs);
    prop_proj_kernel<<<512, 128, 0, stream>>>(attn, emb, w1, invs, h1);
    prop_kernel<<<512, 128, 0, stream>>>(attn, h1, invs, hb);
    logits_kernel<<<8000, 256, 0, stream>>>(hb, wb, out);
}